// Round 13
// baseline (330.392 us; speedup 1.0000x reference)
//
#include <hip/hip_runtime.h>

#define H 1024
#define S 2048
#define B 32
#define M (S*B)
#define NSC 32   // S-chunks of 64 for weighted_sum (each split in 2 internally)

typedef short bf16x8 __attribute__((ext_vector_type(8)));
typedef float f32x4 __attribute__((ext_vector_type(4)));
typedef float f32x16 __attribute__((ext_vector_type(16)));

__device__ __forceinline__ unsigned short f2bf(float f) {
    unsigned int u = __builtin_bit_cast(unsigned int, f);
    u += 0x7FFFu + ((u >> 16) & 1u);
    return (unsigned short)(u >> 16);
}

__device__ __forceinline__ float bf2f(unsigned short s) {
    unsigned int u = (unsigned int)s << 16;
    return __builtin_bit_cast(float, u);
}

__device__ __forceinline__ float tanh_fast(float x) {
    float e = __expf(2.f * x);
    return 1.f - 2.f / (e + 1.f);
}

__device__ __forceinline__ void gload_lds16(const void* g, void* l) {
    __builtin_amdgcn_global_load_lds((const __attribute__((address_space(1))) void*)g,
                                     (__attribute__((address_space(3))) void*)l, 16, 0, 0);
}

// ---------------- fused prep: convert_enc + transpose_we + dec_proj ----------------
__global__ __launch_bounds__(256) void prep(const float* __restrict__ enc,
                                            unsigned short* __restrict__ encBF,
                                            const float* __restrict__ We,
                                            unsigned short* __restrict__ WeT,
                                            const float* __restrict__ dec,
                                            const float* __restrict__ Wd,
                                            float* __restrict__ dvec) {
    __shared__ float shbuf[64 * 65];
    int bid = blockIdx.x, t = threadIdx.x;
    if (bid < 4096) {
        const size_t total = (size_t)M * H / 8;
        for (size_t idx = (size_t)bid * 256 + t; idx < total; idx += (size_t)4096 * 256) {
            const f32x4* p = (const f32x4*)(enc + idx * 8);
            f32x4 x = __builtin_nontemporal_load(p);
            f32x4 y = __builtin_nontemporal_load(p + 1);
            bf16x8 c;
            c[0] = (short)f2bf(x[0]); c[1] = (short)f2bf(x[1]);
            c[2] = (short)f2bf(x[2]); c[3] = (short)f2bf(x[3]);
            c[4] = (short)f2bf(y[0]); c[5] = (short)f2bf(y[1]);
            c[6] = (short)f2bf(y[2]); c[7] = (short)f2bf(y[3]);
            *(bf16x8*)(encBF + idx * 8) = c;
        }
    } else if (bid < 4352) {
        int b2 = bid - 4096;
        int tx = t & 63, ty = t >> 6;
        int n0 = (b2 & 15) * 64, k0 = (b2 >> 4) * 64;
#pragma unroll
        for (int q = 0; q < 16; ++q) {
            int kk = ty * 16 + q;
            shbuf[kk * 65 + tx] = We[(size_t)(k0 + kk) * H + n0 + tx];
        }
        __syncthreads();
#pragma unroll
        for (int q = 0; q < 16; ++q) {
            int nn = ty * 16 + q;
            WeT[(size_t)(n0 + nn) * H + k0 + tx] = f2bf(shbuf[tx * 65 + nn]);
        }
    } else {
        int b3 = bid - 4352;
        int jc = b3 & 3, b = b3 >> 2;
        for (int i = t; i < H; i += 256) shbuf[i] = dec[b * H + i];
        __syncthreads();
        int j = jc * 256 + t;
        float acc = 0.f;
#pragma unroll 8
        for (int h = 0; h < H; ++h) acc += shbuf[h] * Wd[(size_t)h * H + j];
        dvec[b * H + j] = acc;
    }
}

// ---------------- m97-structure fused GEMM, 32x32x16 MFMA ----------------
// Same LDS layout/staging as the proven 16x16 version (conflict-free slot-XOR);
// per wave: 2x2 tiles of 32x32. A/B lane map: row/col=lane&31, k=(lane>>5)*8+e.
// C/D: col=lane&31, row=(reg&3)+8*(reg>>2)+4*(lane>>5)  [m74/m101 verified].
__global__ __launch_bounds__(256) void gemm_logits32(const unsigned short* __restrict__ encBF,
                                                     const unsigned short* __restrict__ WeT,
                                                     const float* __restrict__ dvec,
                                                     const float* __restrict__ v,
                                                     float* __restrict__ part) {
    __shared__ unsigned short As[128 * 64];
    __shared__ unsigned short Bs[128 * 64];
    int tid = threadIdx.x, bid = blockIdx.x;
    int swz = (bid & 7) * 512 + (bid >> 3);   // XCD-chunked, bijective (4096 % 8 == 0)
    int bm = swz >> 3, bn = swz & 7;
    int lane = tid & 63, wid = tid >> 6;
    int wm = wid >> 1, wn = wid & 1;
    int l31 = lane & 31, hi = lane >> 5;

    f32x16 acc[2][2] = {};

    int rsub = lane >> 3;
    int gslot = (lane & 7) ^ rsub;
    const unsigned short* aP[4];
    const unsigned short* bP[4];
    unsigned short* aL[4];
    unsigned short* bL[4];
#pragma unroll
    for (int q = 0; q < 4; ++q) {
        int c = wid * 4 + q;
        int grow = c * 8 + rsub;
        aP[q] = encBF + (size_t)(bm * 128 + grow) * H + gslot * 8;
        bP[q] = WeT + (size_t)(bn * 128 + grow) * H + gslot * 8;
        aL[q] = &As[c * 512];
        bL[q] = &Bs[c * 512];
    }

    for (int kt = 0; kt < 16; ++kt) {
        if (kt) __syncthreads();
#pragma unroll
        for (int q = 0; q < 4; ++q) gload_lds16(aP[q] + kt * 64, aL[q]);
#pragma unroll
        for (int q = 0; q < 4; ++q) gload_lds16(bP[q] + kt * 64, bL[q]);
        __syncthreads();
#pragma unroll
        for (int ks = 0; ks < 4; ++ks) {
            bf16x8 a[2], bfr[2];
#pragma unroll
            for (int mt = 0; mt < 2; ++mt) {
                int row = wm * 64 + mt * 32 + l31;
                int slot = (ks * 2 + hi) ^ (row & 7);
                a[mt] = *(const bf16x8*)&As[row * 64 + slot * 8];
            }
#pragma unroll
            for (int nt = 0; nt < 2; ++nt) {
                int row = wn * 64 + nt * 32 + l31;
                int slot = (ks * 2 + hi) ^ (row & 7);
                bfr[nt] = *(const bf16x8*)&Bs[row * 64 + slot * 8];
            }
#pragma unroll
            for (int mt = 0; mt < 2; ++mt)
#pragma unroll
                for (int nt = 0; nt < 2; ++nt)
                    acc[mt][nt] = __builtin_amdgcn_mfma_f32_32x32x16_bf16(a[mt], bfr[nt], acc[mt][nt], 0, 0, 0);
        }
    }

    // epilogue: per-wave partial logit over its 64 j's
    float vj[2];
#pragma unroll
    for (int nt = 0; nt < 2; ++nt) vj[nt] = v[bn * 128 + wn * 64 + nt * 32 + l31];
    float pv[2][16];
#pragma unroll
    for (int mt = 0; mt < 2; ++mt) {
#pragma unroll
        for (int reg = 0; reg < 16; ++reg) {
            int rloc = (reg & 3) + 8 * (reg >> 2) + 4 * hi;
            int rg = bm * 128 + wm * 64 + mt * 32 + rloc;
            int bb = rg & (B - 1);   // row = s*B + b
            float p = 0.f;
#pragma unroll
            for (int nt = 0; nt < 2; ++nt) {
                int j = bn * 128 + wn * 64 + nt * 32 + l31;
                p += vj[nt] * tanh_fast(dvec[bb * H + j] + acc[mt][nt][reg]);
            }
            p += __shfl_xor(p, 1);
            p += __shfl_xor(p, 2);
            p += __shfl_xor(p, 4);
            p += __shfl_xor(p, 8);
            p += __shfl_xor(p, 16);
            pv[mt][reg] = p;
        }
    }
    // combine the two wn-halves via LDS
    __syncthreads();
    float* red = (float*)As;
    if (wn == 1) {
#pragma unroll
        for (int mt = 0; mt < 2; ++mt)
#pragma unroll
            for (int reg = 0; reg < 16; ++reg) {
                int rloc = (reg & 3) + 8 * (reg >> 2) + 4 * hi;
                if (l31 == rloc) red[wm * 64 + mt * 32 + rloc] = pv[mt][reg];
            }
    }
    __syncthreads();
    if (wn == 0) {
#pragma unroll
        for (int mt = 0; mt < 2; ++mt)
#pragma unroll
            for (int reg = 0; reg < 16; ++reg) {
                int rloc = (reg & 3) + 8 * (reg >> 2) + 4 * hi;
                if (l31 == rloc) {
                    int rl = wm * 64 + mt * 32 + rloc;
                    int rg = bm * 128 + rl;
                    part[(size_t)rg * 8 + bn] = pv[mt][reg] + red[rl];
                }
            }
    }
}

// ---------------- softmax over s per b (1024 threads, 2 iters) ----------------
__global__ __launch_bounds__(1024) void softmax_k(const float* __restrict__ part,
                                                  float* __restrict__ scores) {
    int b = blockIdx.x, tid = threadIdx.x;
    int lane = tid & 63, wid = tid >> 6;
    __shared__ float red[16];
    __shared__ float red2[16];
    float lg[2];
    float mx = -1e30f;
#pragma unroll
    for (int q = 0; q < 2; ++q) {
        int s = q * 1024 + tid;
        const float4* pr = (const float4*)(part + ((size_t)(s * B + b)) * 8);
        float4 x = pr[0], y = pr[1];
        float L = ((x.x + x.y) + (x.z + x.w)) + ((y.x + y.y) + (y.z + y.w));
        lg[q] = L;
        mx = fmaxf(mx, L);
    }
#pragma unroll
    for (int off = 32; off; off >>= 1) mx = fmaxf(mx, __shfl_xor(mx, off));
    if (lane == 0) red[wid] = mx;
    __syncthreads();
    mx = red[0];
#pragma unroll
    for (int w = 1; w < 16; ++w) mx = fmaxf(mx, red[w]);
    float sum = 0.f;
#pragma unroll
    for (int q = 0; q < 2; ++q) {
        lg[q] = expf(lg[q] - mx);
        sum += lg[q];
    }
#pragma unroll
    for (int off = 32; off; off >>= 1) sum += __shfl_xor(sum, off);
    if (lane == 0) red2[wid] = sum;
    __syncthreads();
    sum = 0.f;
#pragma unroll
    for (int w = 0; w < 16; ++w) sum += red2[w];
    float inv = 1.f / sum;
#pragma unroll
    for (int q = 0; q < 2; ++q) scores[b * S + q * 1024 + tid] = lg[q] * inv;
}

// ---------------- attn_values partials: bf16x8 (16 B/lane), 32-s subchunks ----------------
__global__ __launch_bounds__(256) void weighted_sum(const unsigned short* __restrict__ encBF,
                                                    const float* __restrict__ scores,
                                                    float* __restrict__ part2) {
    __shared__ float sl[64];
    int t = threadIdx.x, b = blockIdx.x, sc = blockIdx.y;
    if (t < 64) sl[t] = scores[b * S + sc * 64 + t];
    __syncthreads();
    int half = t >> 7;            // 0/1: which 32-s subchunk
    int hx = (t & 127) * 8;       // h offset (bf16x8 = 16 B)
    const unsigned short* ep = encBF + ((size_t)(sc * 64 + half * 32) * B + b) * H + hx;
    float a[8] = {};
#pragma unroll 4
    for (int s = 0; s < 32; ++s) {
        bf16x8 e = *(const bf16x8*)(ep + (size_t)s * B * H);
        float w = sl[half * 32 + s];
#pragma unroll
        for (int k = 0; k < 8; ++k) a[k] += bf2f((unsigned short)e[k]) * w;
    }
    float4* dst = (float4*)(part2 + ((size_t)(sc * 2 + half) * B + b) * H + hx);
    dst[0] = make_float4(a[0], a[1], a[2], a[3]);
    dst[1] = make_float4(a[4], a[5], a[6], a[7]);
}

__global__ __launch_bounds__(256) void reduce_vals(const float* __restrict__ part2,
                                                   float* __restrict__ out) {
    int i4 = blockIdx.x * 256 + threadIdx.x;   // over B*H/4 = 8192
    const float4* p4 = (const float4*)part2;
    float4 a = {0.f, 0.f, 0.f, 0.f};
#pragma unroll
    for (int c = 0; c < 2 * NSC; ++c) {
        float4 e = p4[(size_t)c * (B * H / 4) + i4];
        a.x += e.x; a.y += e.y; a.z += e.z; a.w += e.w;
    }
    ((float4*)out)[i4] = a;
}

extern "C" void kernel_launch(void* const* d_in, const int* in_sizes, int n_in,
                              void* d_out, int out_size, void* d_ws, size_t ws_size,
                              hipStream_t stream) {
    const float* dec = (const float*)d_in[0];   // [1,B,H]
    const float* enc = (const float*)d_in[1];   // [S,B,H]
    const float* Wd  = (const float*)d_in[2];   // [H,H]
    const float* We  = (const float*)d_in[3];   // [H,H]
    const float* v   = (const float*)d_in[4];   // [H]
    float* out = (float*)d_out;                 // [B*H] values, then [B*S] scores

    char* ws = (char*)d_ws;
    float* part  = (float*)ws;
    float* part2 = (float*)ws;
    unsigned short* WeT = (unsigned short*)(ws + (4u << 20));
    float* dvec  = (float*)(ws + (6u << 20));
    unsigned short* encBF = (unsigned short*)(ws + ((size_t)8 << 20));

    prep<<<4480, 256, 0, stream>>>(enc, encBF, We, WeT, dec, Wd, dvec);
    gemm_logits32<<<4096, 256, 0, stream>>>(encBF, WeT, dvec, v, part);
    softmax_k<<<B, 1024, 0, stream>>>(part, out + B * H);
    weighted_sum<<<dim3(B, NSC), 256, 0, stream>>>(encBF, out + B * H, part2);
    reduce_vals<<<32, 256, 0, stream>>>(part2, out);
}

// Round 14
// 299.390 us; speedup vs baseline: 1.1035x; 1.1035x over previous
//
#include <hip/hip_runtime.h>

#define H 1024
#define S 2048
#define B 32
#define M (S*B)
#define NSC 32   // S-chunks of 64 for weighted_sum (each split in 2 internally)

typedef short bf16x8 __attribute__((ext_vector_type(8)));
typedef float f32x4 __attribute__((ext_vector_type(4)));

__device__ __forceinline__ unsigned short f2bf(float f) {
    unsigned int u = __builtin_bit_cast(unsigned int, f);
    u += 0x7FFFu + ((u >> 16) & 1u);
    return (unsigned short)(u >> 16);
}

__device__ __forceinline__ float bf2f(unsigned short s) {
    unsigned int u = (unsigned int)s << 16;
    return __builtin_bit_cast(float, u);
}

__device__ __forceinline__ float tanh_fast(float x) {
    float e = __expf(2.f * x);
    return 1.f - 2.f / (e + 1.f);
}

__device__ __forceinline__ void gload_lds16(const void* g, void* l) {
    __builtin_amdgcn_global_load_lds((const __attribute__((address_space(1))) void*)g,
                                     (__attribute__((address_space(3))) void*)l, 16, 0, 0);
}

// ---------------- fused prep: convert_enc + transpose_we + dec_proj ----------------
// blocks [0,4096): enc f32->bf16 (nt loads: f32 enc is never re-read);
// [4096,4352): We->WeT bf16; [4352,4480): dvec
__global__ __launch_bounds__(256) void prep(const float* __restrict__ enc,
                                            unsigned short* __restrict__ encBF,
                                            const float* __restrict__ We,
                                            unsigned short* __restrict__ WeT,
                                            const float* __restrict__ dec,
                                            const float* __restrict__ Wd,
                                            float* __restrict__ dvec) {
    __shared__ float shbuf[64 * 65];
    int bid = blockIdx.x, t = threadIdx.x;
    if (bid < 4096) {
        const size_t total = (size_t)M * H / 8;
        for (size_t idx = (size_t)bid * 256 + t; idx < total; idx += (size_t)4096 * 256) {
            const f32x4* p = (const f32x4*)(enc + idx * 8);
            f32x4 x = __builtin_nontemporal_load(p);
            f32x4 y = __builtin_nontemporal_load(p + 1);
            bf16x8 c;
            c[0] = (short)f2bf(x[0]); c[1] = (short)f2bf(x[1]);
            c[2] = (short)f2bf(x[2]); c[3] = (short)f2bf(x[3]);
            c[4] = (short)f2bf(y[0]); c[5] = (short)f2bf(y[1]);
            c[6] = (short)f2bf(y[2]); c[7] = (short)f2bf(y[3]);
            *(bf16x8*)(encBF + idx * 8) = c;
        }
    } else if (bid < 4352) {
        int b2 = bid - 4096;
        int tx = t & 63, ty = t >> 6;
        int n0 = (b2 & 15) * 64, k0 = (b2 >> 4) * 64;
#pragma unroll
        for (int q = 0; q < 16; ++q) {
            int kk = ty * 16 + q;
            shbuf[kk * 65 + tx] = We[(size_t)(k0 + kk) * H + n0 + tx];
        }
        __syncthreads();
#pragma unroll
        for (int q = 0; q < 16; ++q) {
            int nn = ty * 16 + q;
            WeT[(size_t)(n0 + nn) * H + k0 + tx] = f2bf(shbuf[tx * 65 + nn]);
        }
    } else {
        int b3 = bid - 4352;
        int jc = b3 & 3, b = b3 >> 2;
        for (int i = t; i < H; i += 256) shbuf[i] = dec[b * H + i];
        __syncthreads();
        int j = jc * 256 + t;
        float acc = 0.f;
#pragma unroll 8
        for (int h = 0; h < H; ++h) acc += shbuf[h] * Wd[(size_t)h * H + j];
        dvec[b * H + j] = acc;
    }
}

// ---------------- m97-structure fused GEMM (R8/R12-proven) ----------------
__global__ __launch_bounds__(256) void gemm_logits2(const unsigned short* __restrict__ encBF,
                                                    const unsigned short* __restrict__ WeT,
                                                    const float* __restrict__ dvec,
                                                    const float* __restrict__ v,
                                                    float* __restrict__ part) {
    __shared__ unsigned short As[128 * 64];
    __shared__ unsigned short Bs[128 * 64];
    int tid = threadIdx.x, bid = blockIdx.x;
    int swz = (bid & 7) * 512 + (bid >> 3);   // XCD-chunked, bijective (4096 % 8 == 0)
    int bm = swz >> 3, bn = swz & 7;
    int lane = tid & 63, wid = tid >> 6;
    int wm = wid >> 1, wn = wid & 1;

    f32x4 acc[4][4] = {};

    int rsub = lane >> 3;
    int gslot = (lane & 7) ^ rsub;
    const unsigned short* aP[4];
    const unsigned short* bP[4];
    unsigned short* aL[4];
    unsigned short* bL[4];
#pragma unroll
    for (int q = 0; q < 4; ++q) {
        int c = wid * 4 + q;
        int grow = c * 8 + rsub;
        aP[q] = encBF + (size_t)(bm * 128 + grow) * H + gslot * 8;
        bP[q] = WeT + (size_t)(bn * 128 + grow) * H + gslot * 8;
        aL[q] = &As[c * 512];
        bL[q] = &Bs[c * 512];
    }

    for (int kt = 0; kt < 16; ++kt) {
        if (kt) __syncthreads();
#pragma unroll
        for (int q = 0; q < 4; ++q) gload_lds16(aP[q] + kt * 64, aL[q]);
#pragma unroll
        for (int q = 0; q < 4; ++q) gload_lds16(bP[q] + kt * 64, bL[q]);
        __syncthreads();
#pragma unroll
        for (int kh = 0; kh < 2; ++kh) {
            bf16x8 a[4], bfr[4];
#pragma unroll
            for (int m = 0; m < 4; ++m) {
                int row = wm * 64 + m * 16 + (lane & 15);
                int slot = (kh * 4 + (lane >> 4)) ^ (row & 7);
                a[m] = *(const bf16x8*)&As[row * 64 + slot * 8];
            }
#pragma unroll
            for (int n = 0; n < 4; ++n) {
                int row = wn * 64 + n * 16 + (lane & 15);
                int slot = (kh * 4 + (lane >> 4)) ^ (row & 7);
                bfr[n] = *(const bf16x8*)&Bs[row * 64 + slot * 8];
            }
#pragma unroll
            for (int m = 0; m < 4; ++m)
#pragma unroll
                for (int n = 0; n < 4; ++n)
                    acc[m][n] = __builtin_amdgcn_mfma_f32_16x16x32_bf16(a[m], bfr[n], acc[m][n], 0, 0, 0);
        }
    }

    float vj[4];
#pragma unroll
    for (int n = 0; n < 4; ++n) vj[n] = v[bn * 128 + wn * 64 + n * 16 + (lane & 15)];
    float pv[4][4];
#pragma unroll
    for (int m = 0; m < 4; ++m) {
#pragma unroll
        for (int i = 0; i < 4; ++i) {
            int rg = bm * 128 + wm * 64 + m * 16 + (lane >> 4) * 4 + i;
            int bb = rg & (B - 1);   // row = s*B + b
            float p = 0.f;
#pragma unroll
            for (int n = 0; n < 4; ++n) {
                int j = bn * 128 + wn * 64 + n * 16 + (lane & 15);
                p += vj[n] * tanh_fast(dvec[bb * H + j] + acc[m][n][i]);
            }
            p += __shfl_xor(p, 1);
            p += __shfl_xor(p, 2);
            p += __shfl_xor(p, 4);
            p += __shfl_xor(p, 8);
            pv[m][i] = p;
        }
    }
    __syncthreads();
    float* red = (float*)As;
    if (wn == 1) {
#pragma unroll
        for (int m = 0; m < 4; ++m)
#pragma unroll
            for (int i = 0; i < 4; ++i) {
                int rl = wm * 64 + m * 16 + (lane >> 4) * 4 + i;
                if ((lane & 15) == 0) red[rl] = pv[m][i];
            }
    }
    __syncthreads();
    if (wn == 0) {
#pragma unroll
        for (int m = 0; m < 4; ++m)
#pragma unroll
            for (int i = 0; i < 4; ++i) {
                int rl = wm * 64 + m * 16 + (lane >> 4) * 4 + i;
                int rg = bm * 128 + rl;
                if ((lane & 15) == 0) part[(size_t)rg * 8 + bn] = pv[m][i] + red[rl];
            }
    }
}

// ---------------- softmax over s per b (1024 threads, 2 iters) ----------------
__global__ __launch_bounds__(1024) void softmax_k(const float* __restrict__ part,
                                                  float* __restrict__ scores) {
    int b = blockIdx.x, tid = threadIdx.x;
    int lane = tid & 63, wid = tid >> 6;
    __shared__ float red[16];
    __shared__ float red2[16];
    float lg[2];
    float mx = -1e30f;
#pragma unroll
    for (int q = 0; q < 2; ++q) {
        int s = q * 1024 + tid;
        const float4* pr = (const float4*)(part + ((size_t)(s * B + b)) * 8);
        float4 x = pr[0], y = pr[1];
        float L = ((x.x + x.y) + (x.z + x.w)) + ((y.x + y.y) + (y.z + y.w));
        lg[q] = L;
        mx = fmaxf(mx, L);
    }
#pragma unroll
    for (int off = 32; off; off >>= 1) mx = fmaxf(mx, __shfl_xor(mx, off));
    if (lane == 0) red[wid] = mx;
    __syncthreads();
    mx = red[0];
#pragma unroll
    for (int w = 1; w < 16; ++w) mx = fmaxf(mx, red[w]);
    float sum = 0.f;
#pragma unroll
    for (int q = 0; q < 2; ++q) {
        lg[q] = expf(lg[q] - mx);
        sum += lg[q];
    }
#pragma unroll
    for (int off = 32; off; off >>= 1) sum += __shfl_xor(sum, off);
    if (lane == 0) red2[wid] = sum;
    __syncthreads();
    sum = 0.f;
#pragma unroll
    for (int w = 0; w < 16; ++w) sum += red2[w];
    float inv = 1.f / sum;
#pragma unroll
    for (int q = 0; q < 2; ++q) scores[b * S + q * 1024 + tid] = lg[q] * inv;
}

// ---------------- attn_values partials: bf16x8 (16 B/lane), 32-s subchunks ----------------
__global__ __launch_bounds__(256) void weighted_sum(const unsigned short* __restrict__ encBF,
                                                    const float* __restrict__ scores,
                                                    float* __restrict__ part2) {
    __shared__ float sl[64];
    int t = threadIdx.x, b = blockIdx.x, sc = blockIdx.y;
    if (t < 64) sl[t] = scores[b * S + sc * 64 + t];
    __syncthreads();
    int half = t >> 7;            // 0/1: which 32-s subchunk
    int hx = (t & 127) * 8;       // h offset (bf16x8 = 16 B)
    const unsigned short* ep = encBF + ((size_t)(sc * 64 + half * 32) * B + b) * H + hx;
    float a[8] = {};
#pragma unroll 4
    for (int s = 0; s < 32; ++s) {
        bf16x8 e = *(const bf16x8*)(ep + (size_t)s * B * H);
        float w = sl[half * 32 + s];
#pragma unroll
        for (int k = 0; k < 8; ++k) a[k] += bf2f((unsigned short)e[k]) * w;
    }
    float4* dst = (float4*)(part2 + ((size_t)(sc * 2 + half) * B + b) * H + hx);
    dst[0] = make_float4(a[0], a[1], a[2], a[3]);
    dst[1] = make_float4(a[4], a[5], a[6], a[7]);
}

__global__ __launch_bounds__(256) void reduce_vals(const float* __restrict__ part2,
                                                   float* __restrict__ out) {
    int i4 = blockIdx.x * 256 + threadIdx.x;   // over B*H/4 = 8192
    const float4* p4 = (const float4*)part2;
    float4 a = {0.f, 0.f, 0.f, 0.f};
#pragma unroll
    for (int c = 0; c < 2 * NSC; ++c) {
        float4 e = p4[(size_t)c * (B * H / 4) + i4];
        a.x += e.x; a.y += e.y; a.z += e.z; a.w += e.w;
    }
    ((float4*)out)[i4] = a;
}

extern "C" void kernel_launch(void* const* d_in, const int* in_sizes, int n_in,
                              void* d_out, int out_size, void* d_ws, size_t ws_size,
                              hipStream_t stream) {
    const float* dec = (const float*)d_in[0];   // [1,B,H]
    const float* enc = (const float*)d_in[1];   // [S,B,H]
    const float* Wd  = (const float*)d_in[2];   // [H,H]
    const float* We  = (const float*)d_in[3];   // [H,H]
    const float* v   = (const float*)d_in[4];   // [H]
    float* out = (float*)d_out;                 // [B*H] values, then [B*S] scores

    // ws layout (dead-buffer overlays):
    //   part : [0, 2MB)      gemm out -> softmax in (dead after softmax)
    //   part2: [0, 8MB)      weighted_sum out -> reduce in (overlays part/WeT/dvec,
    //                        all dead once weighted_sum runs)
    //   WeT  : [4MB, 6MB)    prep out -> gemm in
    //   dvec : [6MB, 6.125)  prep out -> gemm in
    //   encBF: [8MB, 136MB)  prep out -> gemm + weighted_sum in
    char* ws = (char*)d_ws;
    float* part  = (float*)ws;
    float* part2 = (float*)ws;
    unsigned short* WeT = (unsigned short*)(ws + (4u << 20));
    float* dvec  = (float*)(ws + (6u << 20));
    unsigned short* encBF = (unsigned short*)(ws + ((size_t)8 << 20));

    prep<<<4480, 256, 0, stream>>>(enc, encBF, We, WeT, dec, Wd, dvec);
    gemm_logits2<<<4096, 256, 0, stream>>>(encBF, WeT, dvec, v, part);
    softmax_k<<<B, 1024, 0, stream>>>(part, out + B * H);
    weighted_sum<<<dim3(B, NSC), 256, 0, stream>>>(encBF, out + B * H, part2);
    reduce_vals<<<32, 256, 0, stream>>>(part2, out);
}